// Round 3
// baseline (1404.462 us; speedup 1.0000x reference)
//
#include <hip/hip_runtime.h>

#define F_IN  128
#define F_OUT 64

// ---------------------------------------------------------------------------
// Kernel 1: h[i] = x[lo+i] @ W + b   for i in [0, cnt)
// Block = 256 threads = 4 waves, 16 nodes/block. W staged in LDS (32 KB),
// x rows staged in LDS (padded stride 132 to avoid bank conflicts).
// ---------------------------------------------------------------------------
__global__ __launch_bounds__(256) void gemm_h_kernel(
    const float* __restrict__ x, const float* __restrict__ W,
    const float* __restrict__ bias, float* __restrict__ h, int lo, int cnt) {
  __shared__ float sW[F_IN * F_OUT];   // 32 KB, row-major [128][64]
  __shared__ float sx[16][132];        // 16 nodes x 128 floats, padded

  const int t = threadIdx.x;
  const int base = blockIdx.x * 16;    // local node index base within chunk

  // Stage W: 2048 float4
  {
    const float4* W4 = (const float4*)W;
    float4* sW4 = (float4*)sW;
#pragma unroll
    for (int j = 0; j < 8; ++j) sW4[t + 256 * j] = W4[t + 256 * j];
  }
  // Stage x rows: 512 float4
  {
#pragma unroll
    for (int j = 0; j < 2; ++j) {
      int idx = t + 256 * j;           // 0..511
      int r = idx >> 5;                // 32 float4 per row
      int c = idx & 31;
      int li = base + r;
      float4 v = make_float4(0.f, 0.f, 0.f, 0.f);
      if (li < cnt) v = ((const float4*)x)[(size_t)(lo + li) * 32 + c];
      *(float4*)&sx[r][c * 4] = v;
    }
  }
  __syncthreads();

  const int wave = t >> 6;
  const int lane = t & 63;
  const int nl = wave * 4 + (lane >> 4);   // 0..15 local node
  const int f0 = (lane & 15) * 4;          // output quad
  const int li = base + nl;

  float4 acc = *(const float4*)&bias[f0];

#pragma unroll
  for (int k = 0; k < F_IN; k += 4) {
    float4 xv = *(const float4*)&sx[nl][k];
#pragma unroll
    for (int j = 0; j < 4; ++j) {
      float4 wv = *(const float4*)&sW[(k + j) * F_OUT + f0];
      float xs = (j == 0) ? xv.x : (j == 1) ? xv.y : (j == 2) ? xv.z : xv.w;
      acc.x += xs * wv.x;
      acc.y += xs * wv.y;
      acc.z += xs * wv.z;
      acc.w += xs * wv.w;
    }
  }

  if (li < cnt) *(float4*)&h[(size_t)li * F_OUT + f0] = acc;
}

// ---------------------------------------------------------------------------
// Kernel 2: ranged scatter-add  out[row[e]] += h[col[e] - lo]  if col in [lo,hi)
// 16 threads per edge, each owns a float4. alpha == softmax over size-1
// axis == 1.0 exactly, so edge weights are identity.
// edge_index arrives as int32 (harness converts all integer inputs to int).
// ---------------------------------------------------------------------------
__global__ __launch_bounds__(256) void scatter_kernel(
    const int* __restrict__ rows, const int* __restrict__ cols,
    const float* __restrict__ h, float* __restrict__ out, int E, int lo, int hi) {
  long long tid = (long long)blockIdx.x * blockDim.x + threadIdx.x;
  int e = (int)(tid >> 4);
  int q = (int)(tid & 15);
  if (e >= E) return;

  int c = cols[e];
  if (c < lo || c >= hi) return;
  int r = rows[e];

  float4 v = ((const float4*)h)[(size_t)(c - lo) * 16 + q];
  float* o = out + (size_t)r * F_OUT + q * 4;
  atomicAdd(o + 0, v.x);
  atomicAdd(o + 1, v.y);
  atomicAdd(o + 2, v.z);
  atomicAdd(o + 3, v.w);
}

// ---------------------------------------------------------------------------
// Ultra-fallback (zero scratch): recompute h[col] per edge on the fly.
// One thread per (edge, feature). Slow but never touches d_ws.
// ---------------------------------------------------------------------------
__global__ __launch_bounds__(256) void fused_kernel(
    const float* __restrict__ x, const float* __restrict__ W,
    const float* __restrict__ bias,
    const int* __restrict__ rows, const int* __restrict__ cols,
    float* __restrict__ out, int E) {
  long long tid = (long long)blockIdx.x * blockDim.x + threadIdx.x;
  int e = (int)(tid >> 6);
  int f = (int)(tid & 63);
  if (e >= E) return;

  int c = cols[e];
  int r = rows[e];
  const float* xr = x + (size_t)c * F_IN;
  float acc = bias[f];
#pragma unroll 8
  for (int k = 0; k < F_IN; ++k) acc += xr[k] * W[k * F_OUT + f];
  atomicAdd(&out[(size_t)r * F_OUT + f], acc);
}

extern "C" void kernel_launch(void* const* d_in, const int* in_sizes, int n_in,
                              void* d_out, int out_size, void* d_ws, size_t ws_size,
                              hipStream_t stream) {
  const float* x    = (const float*)d_in[0];
  const int*   rows = (const int*)d_in[1];        // edge_index[0], int32
  const float* Ww   = (const float*)d_in[2];      // [128, 64]
  const float* Wb   = (const float*)d_in[3];      // [64]
  // d_in[4] (a_w), d_in[5] (a_b) are dead: softmax over a size-1 axis == 1.

  const int N = in_sizes[0] / F_IN;   // 100000
  const int E = in_sizes[1] / 2;      // 1600000
  const int* cols = rows + E;         // edge_index[1]

  float* out = (float*)d_out;
  float* h   = (float*)d_ws;

  // out accumulates -> must be zeroed every call (graph-replay safe).
  hipMemsetAsync(d_out, 0, (size_t)out_size * sizeof(float), stream);

  // How many h-rows (64 floats = 256 B each) fit in the workspace?
  int chunkN = (int)((ws_size / (F_OUT * sizeof(float))) & ~(size_t)15);
  if (chunkN > N) chunkN = N;

  if (chunkN >= 16) {
    // Chunked two-stage path: per node-chunk, GEMM h then ranged scatter.
    int scatterBlocks = (int)(((long long)E * 16 + 255) / 256);
    for (int lo = 0; lo < N; lo += chunkN) {
      int cnt = (N - lo < chunkN) ? (N - lo) : chunkN;
      gemm_h_kernel<<<(cnt + 15) / 16, 256, 0, stream>>>(x, Ww, Wb, h, lo, cnt);
      scatter_kernel<<<scatterBlocks, 256, 0, stream>>>(rows, cols, h, out, E,
                                                        lo, lo + cnt);
    }
  } else {
    // Workspace unusable: fused zero-scratch recompute.
    long long threads = (long long)E * 64;
    int blocks = (int)((threads + 255) / 256);
    fused_kernel<<<blocks, 256, 0, stream>>>(x, Ww, Wb, rows, cols, out, E);
  }
}

// Round 4
// 329.369 us; speedup vs baseline: 4.2641x; 4.2641x over previous
//
#include <hip/hip_runtime.h>

#define F_IN  128
#define F_OUT 64

// ---------------------------------------------------------------------------
// Kernel 1: h[i] = x[lo+i] @ W + b   for i in [0, cnt)
// ---------------------------------------------------------------------------
__global__ __launch_bounds__(256) void gemm_h_kernel(
    const float* __restrict__ x, const float* __restrict__ W,
    const float* __restrict__ bias, float* __restrict__ h, int lo, int cnt) {
  __shared__ float sW[F_IN * F_OUT];   // 32 KB
  __shared__ float sx[16][132];

  const int t = threadIdx.x;
  const int base = blockIdx.x * 16;

  {
    const float4* W4 = (const float4*)W;
    float4* sW4 = (float4*)sW;
#pragma unroll
    for (int j = 0; j < 8; ++j) sW4[t + 256 * j] = W4[t + 256 * j];
  }
  {
#pragma unroll
    for (int j = 0; j < 2; ++j) {
      int idx = t + 256 * j;
      int r = idx >> 5;
      int c = idx & 31;
      int li = base + r;
      float4 v = make_float4(0.f, 0.f, 0.f, 0.f);
      if (li < cnt) v = ((const float4*)x)[(size_t)(lo + li) * 32 + c];
      *(float4*)&sx[r][c * 4] = v;
    }
  }
  __syncthreads();

  const int wave = t >> 6;
  const int lane = t & 63;
  const int nl = wave * 4 + (lane >> 4);
  const int f0 = (lane & 15) * 4;
  const int li = base + nl;

  float4 acc = *(const float4*)&bias[f0];

#pragma unroll
  for (int k = 0; k < F_IN; k += 4) {
    float4 xv = *(const float4*)&sx[nl][k];
#pragma unroll
    for (int j = 0; j < 4; ++j) {
      float4 wv = *(const float4*)&sW[(k + j) * F_OUT + f0];
      float xs = (j == 0) ? xv.x : (j == 1) ? xv.y : (j == 2) ? xv.z : xv.w;
      acc.x += xs * wv.x;
      acc.y += xs * wv.y;
      acc.z += xs * wv.z;
      acc.w += xs * wv.w;
    }
  }

  if (li < cnt) *(float4*)&h[(size_t)li * F_OUT + f0] = acc;
}

// ---------------------------------------------------------------------------
// CSR build: histogram -> scan -> bucket scatter
// ---------------------------------------------------------------------------
__global__ __launch_bounds__(256) void hist_kernel(
    const int* __restrict__ rows, int* __restrict__ cnt, int E) {
  int e = blockIdx.x * blockDim.x + threadIdx.x;
  if (e < E) atomicAdd(&cnt[rows[e]], 1);
}

// Block of 256 threads scans 1024 counts -> exclusive local scan + block total.
__global__ __launch_bounds__(256) void scan1_kernel(
    const int* __restrict__ cnt, int* __restrict__ lscan,
    int* __restrict__ partials, int N) {
  __shared__ int s[256];
  const int b = blockIdx.x, t = threadIdx.x;
  const int base = b * 1024 + t * 4;
  int v0 = 0, v1 = 0, v2 = 0, v3 = 0;
  if (base + 3 < N) {
    int4 v = *(const int4*)&cnt[base];
    v0 = v.x; v1 = v.y; v2 = v.z; v3 = v.w;
  } else {
    if (base     < N) v0 = cnt[base];
    if (base + 1 < N) v1 = cnt[base + 1];
    if (base + 2 < N) v2 = cnt[base + 2];
    if (base + 3 < N) v3 = cnt[base + 3];
  }
  int tsum = v0 + v1 + v2 + v3;
  s[t] = tsum;
  __syncthreads();
  for (int off = 1; off < 256; off <<= 1) {
    int a = (t >= off) ? s[t - off] : 0;
    __syncthreads();
    s[t] += a;
    __syncthreads();
  }
  int excl = s[t] - tsum;
  if (base     < N) lscan[base]     = excl;
  if (base + 1 < N) lscan[base + 1] = excl + v0;
  if (base + 2 < N) lscan[base + 2] = excl + v0 + v1;
  if (base + 3 < N) lscan[base + 3] = excl + v0 + v1 + v2;
  if (t == 255) partials[b] = s[255];
}

// Single-block exclusive scan of up to 256 partials, in place.
__global__ __launch_bounds__(256) void scan2_kernel(int* __restrict__ p, int nb) {
  __shared__ int s[256];
  const int t = threadIdx.x;
  int v = (t < nb) ? p[t] : 0;
  s[t] = v;
  __syncthreads();
  for (int off = 1; off < 256; off <<= 1) {
    int a = (t >= off) ? s[t - off] : 0;
    __syncthreads();
    s[t] += a;
    __syncthreads();
  }
  if (t < nb) p[t] = s[t] - v;   // exclusive
}

// Add block offsets; init cursor; set row_start[N] = E.
__global__ __launch_bounds__(256) void scan3_kernel(
    int* __restrict__ row_start, const int* __restrict__ partials,
    int* __restrict__ cursor, int N, int E) {
  int i = blockIdx.x * blockDim.x + threadIdx.x;
  if (i < N) {
    int v = row_start[i] + partials[i >> 10];
    row_start[i] = v;
    cursor[i] = v;
  }
  if (i == 0) row_start[N] = E;
}

__global__ __launch_bounds__(256) void csr_scatter_kernel(
    const int* __restrict__ rows, const int* __restrict__ cols,
    int* __restrict__ cursor, int* __restrict__ dst, int E) {
  int e = blockIdx.x * blockDim.x + threadIdx.x;
  if (e >= E) return;
  int pos = atomicAdd(&cursor[rows[e]], 1);
  dst[pos] = cols[e];
}

// ---------------------------------------------------------------------------
// Gather: one 64-lane wave per output row; lane owns one feature.
// Zero fp atomics; out written exactly once (rows with deg 0 get zeros).
// ---------------------------------------------------------------------------
__global__ __launch_bounds__(256) void gather_kernel(
    const int* __restrict__ row_start, const int* __restrict__ dst,
    const float* __restrict__ h, float* __restrict__ out, int N) {
  int wid = (int)(((long long)blockIdx.x * blockDim.x + threadIdx.x) >> 6);
  int lane = threadIdx.x & 63;
  if (wid >= N) return;
  int beg = row_start[wid];
  int end = row_start[wid + 1];
  float a0 = 0.f, a1 = 0.f;
  int j = beg;
  for (; j + 1 < end; j += 2) {
    int c0 = dst[j];
    int c1 = dst[j + 1];
    a0 += h[(size_t)c0 * F_OUT + lane];
    a1 += h[(size_t)c1 * F_OUT + lane];
  }
  if (j < end) {
    int c = dst[j];
    a0 += h[(size_t)c * F_OUT + lane];
  }
  out[(size_t)wid * F_OUT + lane] = a0 + a1;
}

// ---------------------------------------------------------------------------
// Fallback kernels (small ws): round-3 chunked atomic path.
// ---------------------------------------------------------------------------
__global__ __launch_bounds__(256) void scatter_kernel(
    const int* __restrict__ rows, const int* __restrict__ cols,
    const float* __restrict__ h, float* __restrict__ out, int E, int lo, int hi) {
  long long tid = (long long)blockIdx.x * blockDim.x + threadIdx.x;
  int e = (int)(tid >> 4);
  int q = (int)(tid & 15);
  if (e >= E) return;
  int c = cols[e];
  if (c < lo || c >= hi) return;
  int r = rows[e];
  float4 v = ((const float4*)h)[(size_t)(c - lo) * 16 + q];
  float* o = out + (size_t)r * F_OUT + q * 4;
  atomicAdd(o + 0, v.x);
  atomicAdd(o + 1, v.y);
  atomicAdd(o + 2, v.z);
  atomicAdd(o + 3, v.w);
}

__global__ __launch_bounds__(256) void fused_kernel(
    const float* __restrict__ x, const float* __restrict__ W,
    const float* __restrict__ bias,
    const int* __restrict__ rows, const int* __restrict__ cols,
    float* __restrict__ out, int E) {
  long long tid = (long long)blockIdx.x * blockDim.x + threadIdx.x;
  int e = (int)(tid >> 6);
  int f = (int)(tid & 63);
  if (e >= E) return;
  int c = cols[e];
  int r = rows[e];
  const float* xr = x + (size_t)c * F_IN;
  float acc = bias[f];
#pragma unroll 8
  for (int k = 0; k < F_IN; ++k) acc += xr[k] * W[k * F_OUT + f];
  atomicAdd(&out[(size_t)r * F_OUT + f], acc);
}

extern "C" void kernel_launch(void* const* d_in, const int* in_sizes, int n_in,
                              void* d_out, int out_size, void* d_ws, size_t ws_size,
                              hipStream_t stream) {
  const float* x    = (const float*)d_in[0];
  const int*   rows = (const int*)d_in[1];        // edge_index row 0 (int32)
  const float* Ww   = (const float*)d_in[2];      // [128, 64]
  const float* Wb   = (const float*)d_in[3];      // [64]
  // d_in[4]/d_in[5] (a_w, a_b) are dead: softmax over a size-1 axis == 1.

  const int N = in_sizes[0] / F_IN;   // 100000
  const int E = in_sizes[1] / 2;      // 1600000
  const int* cols = rows + E;         // edge_index row 1

  float* out = (float*)d_out;
  char*  ws  = (char*)d_ws;

  // --- workspace layout (256B-aligned slices) ---
  size_t off = 0;
  auto alloc = [&](size_t bytes) {
    size_t o = off;
    off = (off + bytes + 255) & ~(size_t)255;
    return o;
  };
  const int nb = (N + 1023) / 1024;                 // scan blocks (98)
  size_t hOff    = alloc((size_t)N * F_OUT * 4);    // 25.6 MB
  size_t cntOff  = alloc((size_t)N * 4);
  size_t rsOff   = alloc((size_t)(N + 1) * 4);
  size_t curOff  = alloc((size_t)N * 4);
  size_t dstOff  = alloc((size_t)E * 4);            // 6.4 MB
  size_t partOff = alloc((size_t)nb * 4);

  const bool csr_ok = (off <= ws_size) && (nb <= 256);

  if (csr_ok) {
    float* h         = (float*)(ws + hOff);
    int*   cnt       = (int*)(ws + cntOff);
    int*   row_start = (int*)(ws + rsOff);
    int*   cursor    = (int*)(ws + curOff);
    int*   dst       = (int*)(ws + dstOff);
    int*   partials  = (int*)(ws + partOff);

    hipMemsetAsync(cnt, 0, (size_t)N * 4, stream);
    gemm_h_kernel<<<(N + 15) / 16, 256, 0, stream>>>(x, Ww, Wb, h, 0, N);
    hist_kernel<<<(E + 255) / 256, 256, 0, stream>>>(rows, cnt, E);
    scan1_kernel<<<nb, 256, 0, stream>>>(cnt, row_start, partials, N);
    scan2_kernel<<<1, 256, 0, stream>>>(partials, nb);
    scan3_kernel<<<(N + 255) / 256, 256, 0, stream>>>(row_start, partials,
                                                      cursor, N, E);
    csr_scatter_kernel<<<(E + 255) / 256, 256, 0, stream>>>(rows, cols, cursor,
                                                            dst, E);
    long long gthreads = (long long)N * 64;
    gather_kernel<<<(int)((gthreads + 255) / 256), 256, 0, stream>>>(
        row_start, dst, h, out, N);
    return;
  }

  // --- fallback: chunked atomic path (proven, ~1.4 ms) ---
  hipMemsetAsync(d_out, 0, (size_t)out_size * sizeof(float), stream);

  int chunkN = (int)((ws_size / (F_OUT * sizeof(float))) & ~(size_t)15);
  if (chunkN > N) chunkN = N;

  if (chunkN >= 16) {
    float* h = (float*)d_ws;
    int scatterBlocks = (int)(((long long)E * 16 + 255) / 256);
    for (int lo = 0; lo < N; lo += chunkN) {
      int cnt2 = (N - lo < chunkN) ? (N - lo) : chunkN;
      gemm_h_kernel<<<(cnt2 + 15) / 16, 256, 0, stream>>>(x, Ww, Wb, h, lo, cnt2);
      scatter_kernel<<<scatterBlocks, 256, 0, stream>>>(rows, cols, h, out, E,
                                                        lo, lo + cnt2);
    }
  } else {
    long long threads = (long long)E * 64;
    int blocks = (int)((threads + 255) / 256);
    fused_kernel<<<blocks, 256, 0, stream>>>(x, Ww, Wb, rows, cols, out, E);
  }
}

// Round 5
// 260.000 us; speedup vs baseline: 5.4018x; 1.2668x over previous
//
#include <hip/hip_runtime.h>

#define F_IN  128
#define F_OUT 64

// ---------------------------------------------------------------------------
// Kernel 1: h[i] = x[lo+i] @ W + b   for i in [0, cnt)
// ---------------------------------------------------------------------------
__global__ __launch_bounds__(256) void gemm_h_kernel(
    const float* __restrict__ x, const float* __restrict__ W,
    const float* __restrict__ bias, float* __restrict__ h, int lo, int cnt) {
  __shared__ float sW[F_IN * F_OUT];   // 32 KB
  __shared__ float sx[16][132];

  const int t = threadIdx.x;
  const int base = blockIdx.x * 16;

  {
    const float4* W4 = (const float4*)W;
    float4* sW4 = (float4*)sW;
#pragma unroll
    for (int j = 0; j < 8; ++j) sW4[t + 256 * j] = W4[t + 256 * j];
  }
  {
#pragma unroll
    for (int j = 0; j < 2; ++j) {
      int idx = t + 256 * j;
      int r = idx >> 5;
      int c = idx & 31;
      int li = base + r;
      float4 v = make_float4(0.f, 0.f, 0.f, 0.f);
      if (li < cnt) v = ((const float4*)x)[(size_t)(lo + li) * 32 + c];
      *(float4*)&sx[r][c * 4] = v;
    }
  }
  __syncthreads();

  const int wave = t >> 6;
  const int lane = t & 63;
  const int nl = wave * 4 + (lane >> 4);
  const int f0 = (lane & 15) * 4;
  const int li = base + nl;

  float4 acc = *(const float4*)&bias[f0];

#pragma unroll
  for (int k = 0; k < F_IN; k += 4) {
    float4 xv = *(const float4*)&sx[nl][k];
#pragma unroll
    for (int j = 0; j < 4; ++j) {
      float4 wv = *(const float4*)&sW[(k + j) * F_OUT + f0];
      float xs = (j == 0) ? xv.x : (j == 1) ? xv.y : (j == 2) ? xv.z : xv.w;
      acc.x += xs * wv.x;
      acc.y += xs * wv.y;
      acc.z += xs * wv.z;
      acc.w += xs * wv.w;
    }
  }

  if (li < cnt) *(float4*)&h[(size_t)li * F_OUT + f0] = acc;
}

// ---------------------------------------------------------------------------
// CSR build: histogram -> scan -> XCD-partitioned bucket scatter
// ---------------------------------------------------------------------------
__global__ __launch_bounds__(256) void hist_kernel(
    const int* __restrict__ rows, int* __restrict__ cnt, int E) {
  int e = blockIdx.x * blockDim.x + threadIdx.x;
  if (e < E) atomicAdd(&cnt[rows[e]], 1);
}

__global__ __launch_bounds__(256) void scan1_kernel(
    const int* __restrict__ cnt, int* __restrict__ lscan,
    int* __restrict__ partials, int N) {
  __shared__ int s[256];
  const int b = blockIdx.x, t = threadIdx.x;
  const int base = b * 1024 + t * 4;
  int v0 = 0, v1 = 0, v2 = 0, v3 = 0;
  if (base + 3 < N) {
    int4 v = *(const int4*)&cnt[base];
    v0 = v.x; v1 = v.y; v2 = v.z; v3 = v.w;
  } else {
    if (base     < N) v0 = cnt[base];
    if (base + 1 < N) v1 = cnt[base + 1];
    if (base + 2 < N) v2 = cnt[base + 2];
    if (base + 3 < N) v3 = cnt[base + 3];
  }
  int tsum = v0 + v1 + v2 + v3;
  s[t] = tsum;
  __syncthreads();
  for (int off = 1; off < 256; off <<= 1) {
    int a = (t >= off) ? s[t - off] : 0;
    __syncthreads();
    s[t] += a;
    __syncthreads();
  }
  int excl = s[t] - tsum;
  if (base     < N) lscan[base]     = excl;
  if (base + 1 < N) lscan[base + 1] = excl + v0;
  if (base + 2 < N) lscan[base + 2] = excl + v0 + v1;
  if (base + 3 < N) lscan[base + 3] = excl + v0 + v1 + v2;
  if (t == 255) partials[b] = s[255];
}

__global__ __launch_bounds__(256) void scan2_kernel(int* __restrict__ p, int nb) {
  __shared__ int s[256];
  const int t = threadIdx.x;
  int v = (t < nb) ? p[t] : 0;
  s[t] = v;
  __syncthreads();
  for (int off = 1; off < 256; off <<= 1) {
    int a = (t >= off) ? s[t - off] : 0;
    __syncthreads();
    s[t] += a;
    __syncthreads();
  }
  if (t < nb) p[t] = s[t] - v;   // exclusive
}

__global__ __launch_bounds__(256) void scan3_kernel(
    int* __restrict__ row_start, const int* __restrict__ partials,
    int* __restrict__ cursor, int N, int E) {
  int i = blockIdx.x * blockDim.x + threadIdx.x;
  if (i < N) {
    int v = row_start[i] + partials[i >> 10];
    row_start[i] = v;
    cursor[i] = v;
  }
  if (i == 0) row_start[N] = E;
}

// XCD-partitioned scatter: block b (XCD b&7 under round-robin dispatch) only
// handles rows in [xcd*rowsPerXcd, (xcd+1)*rowsPerXcd) -> its dst window
// (~800 KB) stays in ONE XCD's L2 and lines are fully written before
// write-back. Each XCD's block-group collectively scans all E edges.
__global__ __launch_bounds__(256) void csr_scatter_part_kernel(
    const int* __restrict__ rows, const int* __restrict__ cols,
    int* __restrict__ cursor, int* __restrict__ dst, int E, int rowsPerXcd) {
  const int b = blockIdx.x;
  const int xcd = b & 7;
  const int grp = b >> 3;
  const int ngrp = gridDim.x >> 3;
  const int lo = xcd * rowsPerXcd;
  const int hi = lo + rowsPerXcd;
  const int chunk = (E + ngrp - 1) / ngrp;
  int beg = grp * chunk;
  int end = beg + chunk; if (end > E) end = E;
  for (int e = beg + threadIdx.x; e < end; e += 256) {
    int r = rows[e];
    if (r >= lo && r < hi) {
      int pos = atomicAdd(&cursor[r], 1);
      dst[pos] = cols[e];
    }
  }
}

// ---------------------------------------------------------------------------
// Gather: one 64-lane wave per output row; lane owns one feature. 4-way ILP.
// ---------------------------------------------------------------------------
__global__ __launch_bounds__(256) void gather_kernel(
    const int* __restrict__ row_start, const int* __restrict__ dst,
    const float* __restrict__ h, float* __restrict__ out, int N) {
  int wid = (int)(((long long)blockIdx.x * blockDim.x + threadIdx.x) >> 6);
  int lane = threadIdx.x & 63;
  if (wid >= N) return;
  int beg = row_start[wid];
  int end = row_start[wid + 1];
  float a0 = 0.f, a1 = 0.f, a2 = 0.f, a3 = 0.f;
  int j = beg;
  for (; j + 3 < end; j += 4) {
    int c0 = dst[j], c1 = dst[j + 1], c2 = dst[j + 2], c3 = dst[j + 3];
    a0 += h[(size_t)c0 * F_OUT + lane];
    a1 += h[(size_t)c1 * F_OUT + lane];
    a2 += h[(size_t)c2 * F_OUT + lane];
    a3 += h[(size_t)c3 * F_OUT + lane];
  }
  for (; j < end; ++j) a0 += h[(size_t)dst[j] * F_OUT + lane];
  out[(size_t)wid * F_OUT + lane] = (a0 + a1) + (a2 + a3);
}

// ---------------------------------------------------------------------------
// Fallback kernels (small ws): chunked atomic path.
// ---------------------------------------------------------------------------
__global__ __launch_bounds__(256) void scatter_kernel(
    const int* __restrict__ rows, const int* __restrict__ cols,
    const float* __restrict__ h, float* __restrict__ out, int E, int lo, int hi) {
  long long tid = (long long)blockIdx.x * blockDim.x + threadIdx.x;
  int e = (int)(tid >> 4);
  int q = (int)(tid & 15);
  if (e >= E) return;
  int c = cols[e];
  if (c < lo || c >= hi) return;
  int r = rows[e];
  float4 v = ((const float4*)h)[(size_t)(c - lo) * 16 + q];
  float* o = out + (size_t)r * F_OUT + q * 4;
  atomicAdd(o + 0, v.x);
  atomicAdd(o + 1, v.y);
  atomicAdd(o + 2, v.z);
  atomicAdd(o + 3, v.w);
}

__global__ __launch_bounds__(256) void fused_kernel(
    const float* __restrict__ x, const float* __restrict__ W,
    const float* __restrict__ bias,
    const int* __restrict__ rows, const int* __restrict__ cols,
    float* __restrict__ out, int E) {
  long long tid = (long long)blockIdx.x * blockDim.x + threadIdx.x;
  int e = (int)(tid >> 6);
  int f = (int)(tid & 63);
  if (e >= E) return;
  int c = cols[e];
  int r = rows[e];
  const float* xr = x + (size_t)c * F_IN;
  float acc = bias[f];
#pragma unroll 8
  for (int k = 0; k < F_IN; ++k) acc += xr[k] * W[k * F_OUT + f];
  atomicAdd(&out[(size_t)r * F_OUT + f], acc);
}

extern "C" void kernel_launch(void* const* d_in, const int* in_sizes, int n_in,
                              void* d_out, int out_size, void* d_ws, size_t ws_size,
                              hipStream_t stream) {
  const float* x    = (const float*)d_in[0];
  const int*   rows = (const int*)d_in[1];        // edge_index row 0 (int32)
  const float* Ww   = (const float*)d_in[2];      // [128, 64]
  const float* Wb   = (const float*)d_in[3];      // [64]
  // d_in[4]/d_in[5] (a_w, a_b) are dead: softmax over a size-1 axis == 1.

  const int N = in_sizes[0] / F_IN;   // 100000
  const int E = in_sizes[1] / 2;      // 1600000
  const int* cols = rows + E;         // edge_index row 1

  float* out = (float*)d_out;
  char*  ws  = (char*)d_ws;

  // --- workspace layout (256B-aligned slices) ---
  size_t off = 0;
  auto alloc = [&](size_t bytes) {
    size_t o = off;
    off = (off + bytes + 255) & ~(size_t)255;
    return o;
  };
  const int nb = (N + 1023) / 1024;                 // scan blocks (98)
  size_t hOff    = alloc((size_t)N * F_OUT * 4);    // 25.6 MB
  size_t cntOff  = alloc((size_t)N * 4);
  size_t rsOff   = alloc((size_t)(N + 1) * 4);
  size_t curOff  = alloc((size_t)N * 4);
  size_t dstOff  = alloc((size_t)E * 4);            // 6.4 MB
  size_t partOff = alloc((size_t)nb * 4);

  const bool csr_ok = (off <= ws_size) && (nb <= 256);

  if (csr_ok) {
    float* h         = (float*)(ws + hOff);
    int*   cnt       = (int*)(ws + cntOff);
    int*   row_start = (int*)(ws + rsOff);
    int*   cursor    = (int*)(ws + curOff);
    int*   dst       = (int*)(ws + dstOff);
    int*   partials  = (int*)(ws + partOff);

    hipMemsetAsync(cnt, 0, (size_t)N * 4, stream);
    gemm_h_kernel<<<(N + 15) / 16, 256, 0, stream>>>(x, Ww, Wb, h, 0, N);
    hist_kernel<<<(E + 255) / 256, 256, 0, stream>>>(rows, cnt, E);
    scan1_kernel<<<nb, 256, 0, stream>>>(cnt, row_start, partials, N);
    scan2_kernel<<<1, 256, 0, stream>>>(partials, nb);
    scan3_kernel<<<(N + 255) / 256, 256, 0, stream>>>(row_start, partials,
                                                      cursor, N, E);
    const int rowsPerXcd = (N + 7) / 8;             // 12500
    csr_scatter_part_kernel<<<2048, 256, 0, stream>>>(rows, cols, cursor, dst,
                                                      E, rowsPerXcd);
    long long gthreads = (long long)N * 64;
    gather_kernel<<<(int)((gthreads + 255) / 256), 256, 0, stream>>>(
        row_start, dst, h, out, N);
    return;
  }

  // --- fallback: chunked atomic path (proven, ~1.4 ms) ---
  hipMemsetAsync(d_out, 0, (size_t)out_size * sizeof(float), stream);

  int chunkN = (int)((ws_size / (F_OUT * sizeof(float))) & ~(size_t)15);
  if (chunkN > N) chunkN = N;

  if (chunkN >= 16) {
    float* h = (float*)d_ws;
    int scatterBlocks = (int)(((long long)E * 16 + 255) / 256);
    for (int lo = 0; lo < N; lo += chunkN) {
      int cnt2 = (N - lo < chunkN) ? (N - lo) : chunkN;
      gemm_h_kernel<<<(cnt2 + 15) / 16, 256, 0, stream>>>(x, Ww, Wb, h, lo, cnt2);
      scatter_kernel<<<scatterBlocks, 256, 0, stream>>>(rows, cols, h, out, E,
                                                        lo, lo + cnt2);
    }
  } else {
    long long threads = (long long)E * 64;
    int blocks = (int)((threads + 255) / 256);
    fused_kernel<<<blocks, 256, 0, stream>>>(x, Ww, Wb, rows, cols, out, E);
  }
}